// Round 17
// baseline (116.040 us; speedup 1.0000x reference)
//
#include <hip/hip_runtime.h>
#include <hip/hip_bf16.h>

typedef __attribute__((ext_vector_type(8))) short bf16x8;
typedef __attribute__((ext_vector_type(8))) unsigned short ushort8;
typedef __attribute__((ext_vector_type(4))) unsigned short ushort4v;
typedef __attribute__((ext_vector_type(4))) float f32x4;
typedef __attribute__((ext_vector_type(4))) unsigned int uint4v;

#define CIN_  128
#define BATCH 16
#define SP_   3136        // 56*56
#define CO_   256
#define NTOT  50176       // BATCH*SP_

// ws layout:
//   [0, 13778944)            : xp bf16 [16][58][58][128]  zero-padded halo
//   [13778944, 14368768)     : Wt bf16 [9][256][128]
//   [14368768, 14373376)     : Wcnt float[1152]
//   [14373376, 14447104)     : part float[1152][16]
#define XP_BYTES   13778944
#define WT_BYTES   589824
#define WS_NEEDED  14447104

__device__ __forceinline__ unsigned short f2bf(float f) {
    unsigned int u = __float_as_uint(f);
    u = (u + 0x7fffu + ((u >> 16) & 1u)) >> 16;   // RNE
    return (unsigned short)u;
}

__device__ __forceinline__ void gl_lds16(const unsigned short* g, unsigned short* l) {
    __builtin_amdgcn_global_load_lds(
        (const __attribute__((address_space(1))) unsigned int*)g,
        (__attribute__((address_space(3))) unsigned int*)l, 16, 0, 0);
}

// ================= fused aux kernel (proven ~13us) =================
__global__ __launch_bounds__(256) void k_aux(
    const float* __restrict__ x, const float* __restrict__ w,
    unsigned short* __restrict__ Wt, unsigned short* __restrict__ xp,
    float* __restrict__ Wcnt, float* __restrict__ part)
{
    __shared__ float T[64][65];
    __shared__ float red9[4][9];
    const int blk = blockIdx.x;
    const int tid = threadIdx.x;

    if (blk < 288) {
        int base = (blk * 256 + tid) * 4;
        float4 v = *(const float4*)(w + base);
        #pragma unroll
        for (int j = 0; j < 4; ++j) {
            int e = base + j;
            int co = e / 1152;
            int r  = e - co * 1152;
            int ci = r / 9;
            int koff = r - ci * 9;
            Wt[(koff * 256 + co) * 128 + ci] = f2bf(((const float*)&v)[j]);
        }
    } else if (blk < 576) {
        int lane = tid & 63;
        int j = (blk - 288) * 4 + (tid >> 6);
        float c = 0.f;
        for (int co = lane; co < 256; co += 64)
            c += (w[(size_t)co * 1152 + j] != 0.0f) ? 1.f : 0.f;
        #pragma unroll
        for (int s = 32; s > 0; s >>= 1) c += __shfl_down(c, s, 64);
        if (lane == 0) Wcnt[j] = c;
    } else if (blk < 2624) {
        int bc = blk - 576;                       // b*128 + ci
        int ci = bc & 127;
        int b  = bc >> 7;
        const float* xpk = x + (size_t)bc * SP_;
        float cnt[9];
        #pragma unroll
        for (int k = 0; k < 9; ++k) cnt[k] = 0.f;
        for (int e = tid; e < SP_; e += 256) {
            float v = xpk[e];
            if (v != 0.f) {
                int h = e / 56, w_ = e - h * 56;
                float r0 = (h <= 54) ? 1.f : 0.f;
                float r2 = (h >= 1) ? 1.f : 0.f;
                float c0 = (w_ <= 54) ? 1.f : 0.f;
                float c2 = (w_ >= 1) ? 1.f : 0.f;
                cnt[0] += r0 * c0; cnt[1] += r0; cnt[2] += r0 * c2;
                cnt[3] += c0;      cnt[4] += 1.f; cnt[5] += c2;
                cnt[6] += r2 * c0; cnt[7] += r2; cnt[8] += r2 * c2;
            }
        }
        #pragma unroll
        for (int k = 0; k < 9; ++k) {
            #pragma unroll
            for (int s = 32; s > 0; s >>= 1) cnt[k] += __shfl_down(cnt[k], s, 64);
        }
        if ((tid & 63) == 0) {
            #pragma unroll
            for (int k = 0; k < 9; ++k) red9[tid >> 6][k] = cnt[k];
        }
        __syncthreads();
        if (tid < 9) {
            float s = red9[0][tid] + red9[1][tid] + red9[2][tid] + red9[3][tid];
            part[(ci * 9 + tid) * 16 + b] = s;
        }
    } else if (blk < 4192) {
        int i = blk - 2624;
        int sp0 = (i % 49) * 64;
        int rest = i / 49;
        int ci0 = (rest & 1) * 64;
        int b = rest >> 1;
        const float* xb = x + ((size_t)(b * 128 + ci0)) * SP_ + sp0;
        #pragma unroll
        for (int r = 0; r < 16; ++r) {
            const int ci_l = (tid >> 6) * 16 + r;
            const int sp_l = tid & 63;
            T[sp_l][ci_l] = xb[(size_t)ci_l * SP_ + sp_l];
        }
        __syncthreads();
        #pragma unroll
        for (int r = 0; r < 4; ++r) {
            const int sp_l = (tid >> 4) * 4 + r;
            const int cc   = (tid & 15) * 4;
            const int sp = sp0 + sp_l;
            const int oh = sp / 56, ow = sp - oh * 56;
            ushort4v v;
            #pragma unroll
            for (int j = 0; j < 4; ++j) v[j] = f2bf(T[sp_l][cc + j]);
            *(ushort4v*)&xp[(((size_t)b * 58 + oh + 1) * 58 + (ow + 1)) * 128 + ci0 + cc] = v;
        }
    } else {
        int b = blk - 4192;
        if (tid < 228) {
            int oh, ow;
            if (tid < 58)       { oh = 0;            ow = tid; }
            else if (tid < 116) { oh = 57;           ow = tid - 58; }
            else if (tid < 172) { oh = tid - 116 + 1; ow = 0; }
            else                { oh = tid - 172 + 1; ow = 57; }
            unsigned short* p = xp + (((size_t)b * 58 + oh) * 58 + ow) * 128;
            ushort8 z = {};
            #pragma unroll
            for (int j = 0; j < 16; ++j) *(ushort8*)(p + j * 8) = z;
        }
    }
}

// ==== main conv: BM=128 x CO=256, 8 waves (wave tile 64x64), A(xp) staged in
//      ring-2 LDS (32 KB -> 2 blocks/CU), B(Wt) loaded global->VGPR (L2-hot),
//      one barrier per kt, counted vmcnt(10), compiler-laddered B waits ====
__global__ __launch_bounds__(512, 4) void k_convg(
    const unsigned short* __restrict__ xp, const unsigned short* __restrict__ Wt,
    const float* __restrict__ bias, float* __restrict__ out,
    const float* __restrict__ Wcnt, const float* __restrict__ part)
{
    __shared__ __attribute__((aligned(16))) unsigned short Albs[2 * 8192]; // 32 KB

    const int tid  = threadIdx.x;

    if (blockIdx.x == 392) {
        // ---- sparsity scalar (512 threads; tiny; runs in conv's shadow) ----
        __shared__ double red[512];
        double s = 0.0;
        for (int j = tid; j < 1152; j += 512) {
            const float4* p4 = (const float4*)(part + (size_t)j * 16);
            float4 a = p4[0], b = p4[1], c = p4[2], d = p4[3];
            float xs = (a.x + a.y + a.z + a.w) + (b.x + b.y + b.z + b.w)
                     + (c.x + c.y + c.z + c.w) + (d.x + d.y + d.z + d.w);
            s += (double)Wcnt[j] * (double)xs;
        }
        red[tid] = s; __syncthreads();
        for (int k = 256; k > 0; k >>= 1) {
            if (tid < k) red[tid] += red[tid + k];
            __syncthreads();
        }
        if (tid == 0) {
            const double ne = 14797504512.0;
            out[12845056] = (float)((ne - red[0]) / ne);
        }
        return;
    }

    const int lane = tid & 63;
    const int l15  = lane & 15;
    const int cl   = lane >> 4;       // 0-3: k-chunk within 32-ci half
    const int w    = tid >> 6;
    const int wm   = w >> 2;          // 0-1 : 64-row half of the 128-row tile
    const int wn   = w & 3;           // 0-3 : 64-co chunk
    const int n0   = blockIdx.x * 128;

    // A staging source offsets: chunk g=j*512+tid -> row=g>>3 (0..127), phys p=g&7,
    // logical c = p ^ (row&7)  (R2-proven conflict-free involution for 8-chunk rows)
    int xoffA[2];
    #pragma unroll
    for (int j = 0; j < 2; ++j) {
        int g   = j * 512 + tid;
        int row = g >> 3;
        int c   = (g & 7) ^ (row & 7);
        int n   = n0 + row;
        int b   = n / SP_;
        int sp  = n - b * SP_;
        int oh  = sp / 56, ow = sp - oh * 56;
        xoffA[j] = ((b * 58 + oh + 1) * 58 + (ow + 1)) * 128 + c * 8;
    }

    // stage kt's full 128x64 A-tile into buffer (kt&1): 2 vmem instrs/thread
    auto stageA = [&](int kt) {
        int koff = kt >> 1;
        int kd   = koff / 3;
        int xsh  = ((kd - 1) * 58 + (koff - kd * 3 - 1)) * 128 + (kt & 1) * 64;
        unsigned short* dst = Albs + (kt & 1) * 8192;
        #pragma unroll
        for (int j = 0; j < 2; ++j)
            gl_lds16(xp + xsh + xoffA[j], dst + (j * 512 + tid) * 8);
    };

    f32x4 acc[4][4] = {};

    // A frag read: row = wm*64 + m*16 + l15, chunk logical = S*4+cl, phys = log^(row&7)
#define LDA_(BO, S, M)                                                         \
    (*(const bf16x8*)&Albs[(BO) + (wm * 64 + (M) * 16 + l15) * 64 +            \
        ((((S) * 4 + cl) ^ ((wm * 64 + (M) * 16 + l15) & 7)) * 8)])

    stageA(0);                                    // 2 vmem in flight

    #pragma unroll 1
    for (int kt = 0; kt < 18; ++kt) {
        const int bo   = (kt & 1) * 8192;
        const int koff = kt >> 1;
        const int half = kt & 1;

        // B fragments for BOTH 32-ci halves of this kt: global->reg (L2-hot).
        // Plain C loads: compiler tracks deps and inserts counted vmcnt before
        // the consuming MFMAs (leaves the newer stageA(kt+1) in flight).
        bf16x8 bfr[2][4];
        {
            const unsigned short* wb = Wt + koff * 32768 + half * 64 + cl * 8;
            #pragma unroll
            for (int S = 0; S < 2; ++S)
                #pragma unroll
                for (int nn = 0; nn < 4; ++nn)
                    bfr[S][nn] = *(const bf16x8*)(wb + (wn * 64 + nn * 16 + l15) * 128 + S * 32);
        }

        if (kt < 17) {
            stageA(kt + 1);
            // outstanding: stageA(kt)[2], B(kt)[8], stageA(kt+1)[2] = 12
            // drain exactly stageA(kt) (issued a full kt ago):
            asm volatile("s_waitcnt vmcnt(10)" ::: "memory");
        } else {
            // outstanding: stageA(17)[2], B(17)[8] = 10 -> drain stageA(17)
            asm volatile("s_waitcnt vmcnt(8)" ::: "memory");
        }
        __builtin_amdgcn_s_barrier();             // buf (kt&1) ready for all waves

        #pragma unroll
        for (int S = 0; S < 2; ++S) {
            bf16x8 a_[4];
            #pragma unroll
            for (int m = 0; m < 4; ++m) a_[m] = LDA_(bo, S, m);
            __builtin_amdgcn_s_setprio(1);
            #pragma unroll
            for (int m = 0; m < 4; ++m)
                #pragma unroll
                for (int nn = 0; nn < 4; ++nn)
                    acc[m][nn] = __builtin_amdgcn_mfma_f32_16x16x32_bf16(
                        a_[m], bfr[S][nn], acc[m][nn], 0, 0, 0);
            __builtin_amdgcn_s_setprio(0);
        }
        __builtin_amdgcn_s_barrier();             // all reads of buf (kt&1) done
    }

#undef LDA_

    // epilogue: D row = n (A = xp), col = co (B = Wt)
    #pragma unroll
    for (int m = 0; m < 4; ++m) {
        int n  = n0 + wm * 64 + m * 16 + (lane >> 4) * 4;
        int b  = n / SP_;
        int sp = n - b * SP_;
        #pragma unroll
        for (int nn = 0; nn < 4; ++nn) {
            int co = wn * 64 + nn * 16 + l15;
            f32x4 v = acc[m][nn] + bias[co];
            *(f32x4*)&out[((size_t)(b * CO_ + co)) * SP_ + sp] = v;
        }
    }
}

// ================= fallback path (ws too small): R1 kernels =================
__global__ void k_wt(const float* __restrict__ w, unsigned short* __restrict__ Wt) {
    int e = blockIdx.x * 256 + threadIdx.x;
    float v = w[e];
    int co = e / 1152;
    int r  = e - co * 1152;
    int ci = r / 9;
    int koff = r - ci * 9;
    Wt[(koff * 256 + co) * 128 + ci] = f2bf(v);
}

__global__ void k_wcnt(const float* __restrict__ w, float* __restrict__ Wcnt) {
    int j = blockIdx.x;
    int lane = threadIdx.x;
    float c = 0.f;
    for (int co = lane; co < 256; co += 64)
        c += (w[(size_t)co * 1152 + j] != 0.0f) ? 1.f : 0.f;
    #pragma unroll
    for (int s = 32; s > 0; s >>= 1) c += __shfl_down(c, s, 64);
    if (lane == 0) Wcnt[j] = c;
}

__global__ void k_xcnt(const float* __restrict__ x, float* __restrict__ Xcnt) {
    int blk = blockIdx.x;
    int ci = blk & 127;
    const float* xpk = x + (size_t)blk * SP_;
    int tid = threadIdx.x;
    float cnt[9];
    #pragma unroll
    for (int k = 0; k < 9; ++k) cnt[k] = 0.f;
    for (int e = tid; e < SP_; e += 256) {
        float v = xpk[e];
        if (v != 0.f) {
            int h = e / 56, w_ = e - h * 56;
            float r0 = (h <= 54) ? 1.f : 0.f;
            float r2 = (h >= 1) ? 1.f : 0.f;
            float c0 = (w_ <= 54) ? 1.f : 0.f;
            float c2 = (w_ >= 1) ? 1.f : 0.f;
            cnt[0] += r0 * c0; cnt[1] += r0; cnt[2] += r0 * c2;
            cnt[3] += c0;      cnt[4] += 1.f; cnt[5] += c2;
            cnt[6] += r2 * c0; cnt[7] += r2; cnt[8] += r2 * c2;
        }
    }
    #pragma unroll
    for (int k = 0; k < 9; ++k) {
        #pragma unroll
        for (int s = 32; s > 0; s >>= 1) cnt[k] += __shfl_down(cnt[k], s, 64);
    }
    if ((tid & 63) == 0) {
        #pragma unroll
        for (int k = 0; k < 9; ++k)
            atomicAdd(&Xcnt[ci * 9 + k], cnt[k]);
    }
}

__global__ void k_spars_f(const float* __restrict__ Wcnt, const float* __restrict__ Xcnt,
                          float* __restrict__ out_scalar) {
    __shared__ double red[256];
    int t = threadIdx.x;
    double s = 0.0;
    for (int j = t; j < 1152; j += 256)
        s += (double)Wcnt[j] * (double)Xcnt[j];
    red[t] = s; __syncthreads();
    for (int k = 128; k > 0; k >>= 1) {
        if (t < k) red[t] += red[t + k];
        __syncthreads();
    }
    if (t == 0) {
        const double ne = 14797504512.0;
        out_scalar[0] = (float)((ne - red[0]) / ne);
    }
}

__global__ __launch_bounds__(256) void k_conv(
    const float* __restrict__ x, const unsigned short* __restrict__ Wt,
    const float* __restrict__ bias, float* __restrict__ out)
{
    __shared__ __attribute__((aligned(16))) unsigned short AldsF[64][40];
    __shared__ __attribute__((aligned(16))) unsigned short BldsF[64][40];

    const int tid  = threadIdx.x;
    const int lane = tid & 63;
    const int wid  = tid >> 6;
    const int wm   = wid >> 1, wn = wid & 1;

    const int n0  = blockIdx.x * 64;
    const int b   = blockIdx.x / 49;
    const int sp0 = n0 - b * SP_;
    const int co0 = blockIdx.y * 64;

    const int a_co = tid >> 2;
    const int a_ci = (tid & 3) * 8;
    const int b_n  = tid & 63;
    const int b_k0 = (tid >> 6) * 8;

    const int sp = sp0 + b_n;
    const int oh = sp / 56, ow = sp - oh * 56;

    f32x4 acc[2][2] = {};
    const float* xb_base = x + (size_t)b * CIN_ * SP_;

    for (int koff = 0; koff < 9; ++koff) {
        const int dh = koff / 3 - 1, dw = koff - (koff / 3) * 3 - 1;
        const int ih = oh + dh, iw = ow + dw;
        const bool valid = ((unsigned)ih < 56u) && ((unsigned)iw < 56u);
        const float* xb = xb_base + sp + dh * 56 + dw;
        const unsigned short* wp = Wt + ((size_t)(koff * 256 + co0 + a_co)) * 128 + a_ci;

        for (int ci0 = 0; ci0 < 128; ci0 += 32) {
            uint4v av = *(const uint4v*)(wp + ci0);
            *(uint4v*)&AldsF[a_co][a_ci] = av;
            ushort8 bv;
            #pragma unroll
            for (int j = 0; j < 8; ++j) {
                int ci = ci0 + b_k0 + j;
                float v = 0.f;
                if (valid) v = xb[(size_t)ci * SP_];
                bv[j] = f2bf(v);
            }
            *(ushort8*)&BldsF[b_n][b_k0] = bv;
            __syncthreads();

            const int row = lane & 15;
            const int kq  = (lane >> 4) * 8;
            bf16x8 a0 = *(const bf16x8*)&AldsF[wm * 32 + row][kq];
            bf16x8 a1 = *(const bf16x8*)&AldsF[wm * 32 + 16 + row][kq];
            bf16x8 bb0 = *(const bf16x8*)&BldsF[wn * 32 + row][kq];
            bf16x8 bb1 = *(const bf16x8*)&BldsF[wn * 32 + 16 + row][kq];
            acc[0][0] = __builtin_amdgcn_mfma_f32_16x16x32_bf16(a0, bb0, acc[0][0], 0, 0, 0);
            acc[0][1] = __builtin_amdgcn_mfma_f32_16x16x32_bf16(a0, bb1, acc[0][1], 0, 0, 0);
            acc[1][0] = __builtin_amdgcn_mfma_f32_16x16x32_bf16(a1, bb0, acc[1][0], 0, 0, 0);
            acc[1][1] = __builtin_amdgcn_mfma_f32_16x16x32_bf16(a1, bb1, acc[1][1], 0, 0, 0);
            __syncthreads();
        }
    }

    const int col = lane & 15;
    const int rb  = (lane >> 4) * 4;
    #pragma unroll
    for (int f = 0; f < 2; ++f) {
        #pragma unroll
        for (int g = 0; g < 2; ++g) {
            int spc = sp0 + wn * 32 + g * 16 + col;
            #pragma unroll
            for (int r = 0; r < 4; ++r) {
                int co = co0 + wm * 32 + f * 16 + rb + r;
                out[((size_t)(b * CO_ + co)) * SP_ + spc] = acc[f][g][r] + bias[co];
            }
        }
    }
}

extern "C" void kernel_launch(void* const* d_in, const int* in_sizes, int n_in,
                              void* d_out, int out_size, void* d_ws, size_t ws_size,
                              hipStream_t stream) {
    const float* x    = (const float*)d_in[0];
    const float* w    = (const float*)d_in[1];
    const float* bias = (const float*)d_in[2];
    float* out = (float*)d_out;

    if (ws_size >= (size_t)WS_NEEDED) {
        unsigned short* xp = (unsigned short*)d_ws;
        unsigned short* Wt = (unsigned short*)((char*)d_ws + XP_BYTES);
        float* Wcnt = (float*)((char*)d_ws + XP_BYTES + WT_BYTES);
        float* part = Wcnt + 1152;

        hipLaunchKernelGGL(k_aux,   dim3(4208),   dim3(256), 0, stream,
                           x, w, Wt, xp, Wcnt, part);
        hipLaunchKernelGGL(k_convg, dim3(393),    dim3(512), 0, stream,
                           xp, Wt, bias, out, Wcnt, part);
    } else {
        unsigned short* Wt = (unsigned short*)d_ws;
        float* Wcnt = (float*)((char*)d_ws + WT_BYTES);
        float* Xcnt = Wcnt + 1152;

        hipMemsetAsync((void*)Xcnt, 0, 1152 * sizeof(float), stream);
        hipLaunchKernelGGL(k_wt,      dim3(1152),    dim3(256), 0, stream, w, Wt);
        hipLaunchKernelGGL(k_wcnt,    dim3(1152),    dim3(64),  0, stream, w, Wcnt);
        hipLaunchKernelGGL(k_xcnt,    dim3(2048),    dim3(256), 0, stream, x, Xcnt);
        hipLaunchKernelGGL(k_conv,    dim3(784, 4),  dim3(256), 0, stream, x, Wt, bias, out);
        hipLaunchKernelGGL(k_spars_f, dim3(1),       dim3(256), 0, stream, Wcnt, Xcnt,
                           out + 12845056);
    }
}

// Round 18
// 60.123 us; speedup vs baseline: 1.9301x; 1.9301x over previous
//
#include <hip/hip_runtime.h>
#include <hip/hip_bf16.h>

typedef __attribute__((ext_vector_type(8))) short bf16x8;
typedef __attribute__((ext_vector_type(8))) unsigned short ushort8;
typedef __attribute__((ext_vector_type(4))) unsigned short ushort4v;
typedef __attribute__((ext_vector_type(4))) float f32x4;
typedef __attribute__((ext_vector_type(4))) unsigned int uint4v;

#define CIN_  128
#define BATCH 16
#define SP_   3136        // 56*56
#define CO_   256
#define NTOT  50176       // BATCH*SP_

// ws layout:
//   [0, 13778944)            : xp bf16 [16][58][58][128]  zero-padded halo
//   [13778944, 14368768)     : Wt bf16 [9][256][128]
//   [14368768, 14373376)     : Wcnt float[1152]
//   [14373376, 14447104)     : part float[1152][16]
#define XP_BYTES   13778944
#define WT_BYTES   589824
#define WS_NEEDED  14447104

__device__ __forceinline__ unsigned short f2bf(float f) {
    unsigned int u = __float_as_uint(f);
    u = (u + 0x7fffu + ((u >> 16) & 1u)) >> 16;   // RNE
    return (unsigned short)u;
}

__device__ __forceinline__ void gl_lds16(const unsigned short* g, unsigned short* l) {
    __builtin_amdgcn_global_load_lds(
        (const __attribute__((address_space(1))) unsigned int*)g,
        (__attribute__((address_space(3))) unsigned int*)l, 16, 0, 0);
}

// ================= fused aux kernel (proven ~13us) =================
// blocks [0,288)      : weight transform -> Wt bf16
// blocks [288,576)    : Wcnt (1 wave per j, 4 j per block)
// blocks [576,2624)   : Xcnt per-(b,ci) counts -> part[ci*9+k][b]  (no atomics)
// blocks [2624,4192)  : x transpose+pad+bf16 -> xp interior
// blocks [4192,4208)  : xp halo zeroing (one block per b)
__global__ __launch_bounds__(256) void k_aux(
    const float* __restrict__ x, const float* __restrict__ w,
    unsigned short* __restrict__ Wt, unsigned short* __restrict__ xp,
    float* __restrict__ Wcnt, float* __restrict__ part)
{
    __shared__ float T[64][65];
    __shared__ float red9[4][9];
    const int blk = blockIdx.x;
    const int tid = threadIdx.x;

    if (blk < 288) {
        int base = (blk * 256 + tid) * 4;
        float4 v = *(const float4*)(w + base);
        #pragma unroll
        for (int j = 0; j < 4; ++j) {
            int e = base + j;
            int co = e / 1152;
            int r  = e - co * 1152;
            int ci = r / 9;
            int koff = r - ci * 9;
            Wt[(koff * 256 + co) * 128 + ci] = f2bf(((const float*)&v)[j]);
        }
    } else if (blk < 576) {
        int lane = tid & 63;
        int j = (blk - 288) * 4 + (tid >> 6);
        float c = 0.f;
        for (int co = lane; co < 256; co += 64)
            c += (w[(size_t)co * 1152 + j] != 0.0f) ? 1.f : 0.f;
        #pragma unroll
        for (int s = 32; s > 0; s >>= 1) c += __shfl_down(c, s, 64);
        if (lane == 0) Wcnt[j] = c;
    } else if (blk < 2624) {
        int bc = blk - 576;                       // b*128 + ci
        int ci = bc & 127;
        int b  = bc >> 7;
        const float* xpk = x + (size_t)bc * SP_;
        float cnt[9];
        #pragma unroll
        for (int k = 0; k < 9; ++k) cnt[k] = 0.f;
        for (int e = tid; e < SP_; e += 256) {
            float v = xpk[e];
            if (v != 0.f) {
                int h = e / 56, w_ = e - h * 56;
                float r0 = (h <= 54) ? 1.f : 0.f;
                float r2 = (h >= 1) ? 1.f : 0.f;
                float c0 = (w_ <= 54) ? 1.f : 0.f;
                float c2 = (w_ >= 1) ? 1.f : 0.f;
                cnt[0] += r0 * c0; cnt[1] += r0; cnt[2] += r0 * c2;
                cnt[3] += c0;      cnt[4] += 1.f; cnt[5] += c2;
                cnt[6] += r2 * c0; cnt[7] += r2; cnt[8] += r2 * c2;
            }
        }
        #pragma unroll
        for (int k = 0; k < 9; ++k) {
            #pragma unroll
            for (int s = 32; s > 0; s >>= 1) cnt[k] += __shfl_down(cnt[k], s, 64);
        }
        if ((tid & 63) == 0) {
            #pragma unroll
            for (int k = 0; k < 9; ++k) red9[tid >> 6][k] = cnt[k];
        }
        __syncthreads();
        if (tid < 9) {
            float s = red9[0][tid] + red9[1][tid] + red9[2][tid] + red9[3][tid];
            part[(ci * 9 + tid) * 16 + b] = s;
        }
    } else if (blk < 4192) {
        int i = blk - 2624;
        int sp0 = (i % 49) * 64;
        int rest = i / 49;
        int ci0 = (rest & 1) * 64;
        int b = rest >> 1;
        const float* xb = x + ((size_t)(b * 128 + ci0)) * SP_ + sp0;
        #pragma unroll
        for (int r = 0; r < 16; ++r) {
            const int ci_l = (tid >> 6) * 16 + r;
            const int sp_l = tid & 63;
            T[sp_l][ci_l] = xb[(size_t)ci_l * SP_ + sp_l];
        }
        __syncthreads();
        #pragma unroll
        for (int r = 0; r < 4; ++r) {
            const int sp_l = (tid >> 4) * 4 + r;
            const int cc   = (tid & 15) * 4;
            const int sp = sp0 + sp_l;
            const int oh = sp / 56, ow = sp - oh * 56;
            ushort4v v;
            #pragma unroll
            for (int j = 0; j < 4; ++j) v[j] = f2bf(T[sp_l][cc + j]);
            *(ushort4v*)&xp[(((size_t)b * 58 + oh + 1) * 58 + (ow + 1)) * 128 + ci0 + cc] = v;
        }
    } else {
        int b = blk - 4192;
        if (tid < 228) {
            int oh, ow;
            if (tid < 58)       { oh = 0;            ow = tid; }
            else if (tid < 116) { oh = 57;           ow = tid - 58; }
            else if (tid < 172) { oh = tid - 116 + 1; ow = 0; }
            else                { oh = tid - 172 + 1; ow = 57; }
            unsigned short* p = xp + (((size_t)b * 58 + oh) * 58 + ow) * 128;
            ushort8 z = {};
            #pragma unroll
            for (int j = 0; j < 16; ++j) *(ushort8*)(p + j * 8) = z;
        }
    }
}

// ==== main conv (R9-verbatim schedule, 45.2us proven) + spars block (196) ====
// conv: 256x256, BK=64, ring-2 by kt parity, ci-split half-tiles,
//       distance-2 staging, uniform vmcnt(8), compiler-laddered lgkm waits.
// block 196: sparsity scalar from Wcnt+part (1152x16 floats - tiny, runs in shadow).
__global__ __launch_bounds__(512, 2) void k_conv8(
    const unsigned short* __restrict__ xp, const unsigned short* __restrict__ Wt,
    const float* __restrict__ bias, float* __restrict__ out,
    const float* __restrict__ Wcnt, const float* __restrict__ part)
{
    __shared__ __attribute__((aligned(16))) unsigned short Albs[2 * 16384]; // 64 KB
    __shared__ __attribute__((aligned(16))) unsigned short Blbs[2 * 16384]; // 64 KB

    const int tid  = threadIdx.x;

    if (blockIdx.x == 196) {
        // ---- sparsity scalar (512 threads; reuses Albs as scratch; ~2us) ----
        double* red = (double*)Albs;              // 4 KB of the 64 KB
        double s = 0.0;
        for (int j = tid; j < 1152; j += 512) {
            const float4* p4 = (const float4*)(part + (size_t)j * 16);
            float4 a = p4[0], b = p4[1], c = p4[2], d = p4[3];
            float xs = (a.x + a.y + a.z + a.w) + (b.x + b.y + b.z + b.w)
                     + (c.x + c.y + c.z + c.w) + (d.x + d.y + d.z + d.w);
            s += (double)Wcnt[j] * (double)xs;
        }
        red[tid] = s; __syncthreads();
        for (int k = 256; k > 0; k >>= 1) {
            if (tid < k) red[tid] += red[tid + k];
            __syncthreads();
        }
        if (tid == 0) {
            const double ne = 14797504512.0;
            out[12845056] = (float)((ne - red[0]) / ne);
        }
        return;
    }

    const int lane = tid & 63;
    const int l15  = lane & 15;
    const int w    = tid >> 6;
    const int wm   = w >> 2;          // 0-1 : n-half of tile
    const int wn   = w & 3;           // 0-3 : 64-co chunk
    const int n0   = blockIdx.x * 256;

    // staging source offsets: chunk g=j*512+tid -> row=g>>2, phys p=g&3,
    // logical c = p ^ ((row>>1)&3)   (proven conflict-free involution; R9: 0 conflicts)
    int xoffA[2], woffB[2];
    #pragma unroll
    for (int j = 0; j < 2; ++j) {
        int g   = j * 512 + tid;
        int row = g >> 2;
        int c   = (g & 3) ^ ((row >> 1) & 3);
        int n   = n0 + row;
        int b   = n / SP_;
        int sp  = n - b * SP_;
        int oh  = sp / 56, ow = sp - oh * 56;
        xoffA[j] = ((b * 58 + oh + 1) * 58 + (ow + 1)) * 128 + c * 8;
        woffB[j] = row * 128 + c * 8;
    }

    auto stageA = [&](int nb, int xsh, int s) {
        #pragma unroll
        for (int j = 0; j < 2; ++j)
            gl_lds16(xp + xsh + s * 32 + xoffA[j],
                     &Albs[nb + s * 8192 + (j * 512 + tid) * 8]);
    };
    auto stageB = [&](int nb, int wsh, int s) {
        #pragma unroll
        for (int j = 0; j < 2; ++j)
            gl_lds16(Wt + wsh + s * 32 + woffB[j],
                     &Blbs[nb + s * 8192 + (j * 512 + tid) * 8]);
    };

    f32x4 acc[8][4] = {};
    const int cl = lane >> 4;  // logical ci-chunk 0-3 within half

#define LDA_(bo, S, R) \
    (*(const bf16x8*)&Albs[(bo) + (S) * 8192 + ((R) + l15) * 32 + \
        ((cl ^ ((((R) + l15) >> 1) & 3)) * 8)])
#define LDB_(bo, S, R) \
    (*(const bf16x8*)&Blbs[(bo) + (S) * 8192 + ((R) + l15) * 32 + \
        ((cl ^ ((((R) + l15) >> 1) & 3)) * 8)])

// B-frags first, A after; NO forced lgkmcnt(0)/sched_barrier -> compiler
// ladders the waits so MFMAs start as soon as (b0-3, a_m) arrive.
#define PHASE(BO, S, DO_STAGE, NB, XSH, WSH, VMN)                          \
    {                                                                      \
        if (DO_STAGE) { stageA(NB, XSH, S); stageB(NB, WSH, S); }          \
        asm volatile("s_waitcnt vmcnt(" VMN ")" ::: "memory");             \
        __builtin_amdgcn_s_barrier();                                      \
        bf16x8 b_[4], a_[8];                                               \
        _Pragma("unroll")                                                  \
        for (int nn = 0; nn < 4; ++nn) b_[nn] = LDB_(BO, S, wn * 64 + nn * 16);\
        _Pragma("unroll")                                                  \
        for (int m = 0; m < 8; ++m) a_[m] = LDA_(BO, S, wm * 128 + m * 16);\
        __builtin_amdgcn_s_setprio(1);                                     \
        _Pragma("unroll")                                                  \
        for (int m = 0; m < 8; ++m)                                        \
            _Pragma("unroll")                                              \
            for (int nn = 0; nn < 4; ++nn)                                 \
                acc[m][nn] = __builtin_amdgcn_mfma_f32_16x16x32_bf16(      \
                    a_[m], b_[nn], acc[m][nn], 0, 0, 0);                   \
        __builtin_amdgcn_s_setprio(0);                                     \
    }

    // prologue: stage kt0 fully (8 vmem)
    {
        const int xsh0 = (-59) * 128;       // koff=0: dh=dw=-1; ci0=0
        stageA(0, xsh0, 0); stageB(0, 0, 0);
        stageA(0, xsh0, 1); stageB(0, 0, 1);
    }

    for (int kt = 0; kt < 17; ++kt) {
        const int bo = (kt & 1) << 14;
        const int nb = 16384 - bo;
        const int kn = kt + 1;
        const int koffn = kn >> 1;
        const int kdn = koffn / 3;
        const int xshn = ((kdn - 1) * 58 + (koffn - kdn * 3 - 1)) * 128 + (kn & 1) * 64;
        const int wshn = koffn * 32768 + (kn & 1) * 64;
        PHASE(bo, 0, true, nb, xshn, wshn, "8");
        PHASE(bo, 1, true, nb, xshn, wshn, "8");
    }
    // peeled kt = 17 (no staging)
    PHASE(16384, 0, false, 0, 0, 0, "4");
    PHASE(16384, 1, false, 0, 0, 0, "0");

#undef PHASE
#undef LDA_
#undef LDB_

    // epilogue: D row = n (A = xp), col = co (B = Wt)
    #pragma unroll
    for (int m = 0; m < 8; ++m) {
        int n  = n0 + wm * 128 + m * 16 + (lane >> 4) * 4;
        int b  = n / SP_;
        int sp = n - b * SP_;
        #pragma unroll
        for (int nn = 0; nn < 4; ++nn) {
            int co = wn * 64 + nn * 16 + l15;
            f32x4 v = acc[m][nn] + bias[co];
            *(f32x4*)&out[((size_t)(b * CO_ + co)) * SP_ + sp] = v;
        }
    }
}

// ================= fallback path (ws too small): R1 kernels =================
__global__ void k_wt(const float* __restrict__ w, unsigned short* __restrict__ Wt) {
    int e = blockIdx.x * 256 + threadIdx.x;
    float v = w[e];
    int co = e / 1152;
    int r  = e - co * 1152;
    int ci = r / 9;
    int koff = r - ci * 9;
    Wt[(koff * 256 + co) * 128 + ci] = f2bf(v);
}

__global__ void k_wcnt(const float* __restrict__ w, float* __restrict__ Wcnt) {
    int j = blockIdx.x;
    int lane = threadIdx.x;
    float c = 0.f;
    for (int co = lane; co < 256; co += 64)
        c += (w[(size_t)co * 1152 + j] != 0.0f) ? 1.f : 0.f;
    #pragma unroll
    for (int s = 32; s > 0; s >>= 1) c += __shfl_down(c, s, 64);
    if (lane == 0) Wcnt[j] = c;
}

__global__ void k_xcnt(const float* __restrict__ x, float* __restrict__ Xcnt) {
    int blk = blockIdx.x;
    int ci = blk & 127;
    const float* xpk = x + (size_t)blk * SP_;
    int tid = threadIdx.x;
    float cnt[9];
    #pragma unroll
    for (int k = 0; k < 9; ++k) cnt[k] = 0.f;
    for (int e = tid; e < SP_; e += 256) {
        float v = xpk[e];
        if (v != 0.f) {
            int h = e / 56, w_ = e - h * 56;
            float r0 = (h <= 54) ? 1.f : 0.f;
            float r2 = (h >= 1) ? 1.f : 0.f;
            float c0 = (w_ <= 54) ? 1.f : 0.f;
            float c2 = (w_ >= 1) ? 1.f : 0.f;
            cnt[0] += r0 * c0; cnt[1] += r0; cnt[2] += r0 * c2;
            cnt[3] += c0;      cnt[4] += 1.f; cnt[5] += c2;
            cnt[6] += r2 * c0; cnt[7] += r2; cnt[8] += r2 * c2;
        }
    }
    #pragma unroll
    for (int k = 0; k < 9; ++k) {
        #pragma unroll
        for (int s = 32; s > 0; s >>= 1) cnt[k] += __shfl_down(cnt[k], s, 64);
    }
    if ((tid & 63) == 0) {
        #pragma unroll
        for (int k = 0; k < 9; ++k)
            atomicAdd(&Xcnt[ci * 9 + k], cnt[k]);
    }
}

__global__ void k_spars_f(const float* __restrict__ Wcnt, const float* __restrict__ Xcnt,
                          float* __restrict__ out_scalar) {
    __shared__ double red[256];
    int t = threadIdx.x;
    double s = 0.0;
    for (int j = t; j < 1152; j += 256)
        s += (double)Wcnt[j] * (double)Xcnt[j];
    red[t] = s; __syncthreads();
    for (int k = 128; k > 0; k >>= 1) {
        if (t < k) red[t] += red[t + k];
        __syncthreads();
    }
    if (t == 0) {
        const double ne = 14797504512.0;
        out_scalar[0] = (float)((ne - red[0]) / ne);
    }
}

__global__ __launch_bounds__(256) void k_conv(
    const float* __restrict__ x, const unsigned short* __restrict__ Wt,
    const float* __restrict__ bias, float* __restrict__ out)
{
    __shared__ __attribute__((aligned(16))) unsigned short AldsF[64][40];
    __shared__ __attribute__((aligned(16))) unsigned short BldsF[64][40];

    const int tid  = threadIdx.x;
    const int lane = tid & 63;
    const int wid  = tid >> 6;
    const int wm   = wid >> 1, wn = wid & 1;

    const int n0  = blockIdx.x * 64;
    const int b   = blockIdx.x / 49;
    const int sp0 = n0 - b * SP_;
    const int co0 = blockIdx.y * 64;

    const int a_co = tid >> 2;
    const int a_ci = (tid & 3) * 8;
    const int b_n  = tid & 63;
    const int b_k0 = (tid >> 6) * 8;

    const int sp = sp0 + b_n;
    const int oh = sp / 56, ow = sp - oh * 56;

    f32x4 acc[2][2] = {};
    const float* xb_base = x + (size_t)b * CIN_ * SP_;

    for (int koff = 0; koff < 9; ++koff) {
        const int dh = koff / 3 - 1, dw = koff - (koff / 3) * 3 - 1;
        const int ih = oh + dh, iw = ow + dw;
        const bool valid = ((unsigned)ih < 56u) && ((unsigned)iw < 56u);
        const float* xb = xb_base + sp + dh * 56 + dw;
        const unsigned short* wp = Wt + ((size_t)(koff * 256 + co0 + a_co)) * 128 + a_ci;

        for (int ci0 = 0; ci0 < 128; ci0 += 32) {
            uint4v av = *(const uint4v*)(wp + ci0);
            *(uint4v*)&AldsF[a_co][a_ci] = av;
            ushort8 bv;
            #pragma unroll
            for (int j = 0; j < 8; ++j) {
                int ci = ci0 + b_k0 + j;
                float v = 0.f;
                if (valid) v = xb[(size_t)ci * SP_];
                bv[j] = f2bf(v);
            }
            *(ushort8*)&BldsF[b_n][b_k0] = bv;
            __syncthreads();

            const int row = lane & 15;
            const int kq  = (lane >> 4) * 8;
            bf16x8 a0 = *(const bf16x8*)&AldsF[wm * 32 + row][kq];
            bf16x8 a1 = *(const bf16x8*)&AldsF[wm * 32 + 16 + row][kq];
            bf16x8 bb0 = *(const bf16x8*)&BldsF[wn * 32 + row][kq];
            bf16x8 bb1 = *(const bf16x8*)&BldsF[wn * 32 + 16 + row][kq];
            acc[0][0] = __builtin_amdgcn_mfma_f32_16x16x32_bf16(a0, bb0, acc[0][0], 0, 0, 0);
            acc[0][1] = __builtin_amdgcn_mfma_f32_16x16x32_bf16(a0, bb1, acc[0][1], 0, 0, 0);
            acc[1][0] = __builtin_amdgcn_mfma_f32_16x16x32_bf16(a1, bb0, acc[1][0], 0, 0, 0);
            acc[1][1] = __builtin_amdgcn_mfma_f32_16x16x32_bf16(a1, bb1, acc[1][1], 0, 0, 0);
            __syncthreads();
        }
    }

    const int col = lane & 15;
    const int rb  = (lane >> 4) * 4;
    #pragma unroll
    for (int f = 0; f < 2; ++f) {
        #pragma unroll
        for (int g = 0; g < 2; ++g) {
            int spc = sp0 + wn * 32 + g * 16 + col;
            #pragma unroll
            for (int r = 0; r < 4; ++r) {
                int co = co0 + wm * 32 + f * 16 + rb + r;
                out[((size_t)(b * CO_ + co)) * SP_ + spc] = acc[f][g][r] + bias[co];
            }
        }
    }
}

extern "C" void kernel_launch(void* const* d_in, const int* in_sizes, int n_in,
                              void* d_out, int out_size, void* d_ws, size_t ws_size,
                              hipStream_t stream) {
    const float* x    = (const float*)d_in[0];
    const float* w    = (const float*)d_in[1];
    const float* bias = (const float*)d_in[2];
    float* out = (float*)d_out;

    if (ws_size >= (size_t)WS_NEEDED) {
        unsigned short* xp = (unsigned short*)d_ws;
        unsigned short* Wt = (unsigned short*)((char*)d_ws + XP_BYTES);
        float* Wcnt = (float*)((char*)d_ws + XP_BYTES + WT_BYTES);
        float* part = Wcnt + 1152;

        hipLaunchKernelGGL(k_aux,   dim3(4208),   dim3(256), 0, stream,
                           x, w, Wt, xp, Wcnt, part);
        hipLaunchKernelGGL(k_conv8, dim3(197),    dim3(512), 0, stream,
                           xp, Wt, bias, out, Wcnt, part);
    } else {
        unsigned short* Wt = (unsigned short*)d_ws;
        float* Wcnt = (float*)((char*)d_ws + WT_BYTES);
        float* Xcnt = Wcnt + 1152;

        hipMemsetAsync((void*)Xcnt, 0, 1152 * sizeof(float), stream);
        hipLaunchKernelGGL(k_wt,      dim3(1152),    dim3(256), 0, stream, w, Wt);
        hipLaunchKernelGGL(k_wcnt,    dim3(1152),    dim3(64),  0, stream, w, Wcnt);
        hipLaunchKernelGGL(k_xcnt,    dim3(2048),    dim3(256), 0, stream, x, Xcnt);
        hipLaunchKernelGGL(k_conv,    dim3(784, 4),  dim3(256), 0, stream, x, Wt, bias, out);
        hipLaunchKernelGGL(k_spars_f, dim3(1),       dim3(256), 0, stream, Wcnt, Xcnt,
                           out + 12845056);
    }
}